// Round 8
// baseline (151.526 us; speedup 1.0000x reference)
//
#include <hip/hip_runtime.h>

#define BATCH 4096
#define NF 128
#define NW 128
#define NO 32
#define MT 128    // batch rows per block
#define LDH 136   // h stride in u16 (272B rows: 16B-aligned)
#define FPB 2     // features per block

// d_ws (u16 elems): wh fp16 [l,f][v][k] | wo fp16 [f][o][k]  (k contiguous)
#define WH_ELEMS (2 * 128 * 128 * 128)
#define WO_ELEMS (128 * 128 * 32)

typedef _Float16 f16x8 __attribute__((ext_vector_type(8)));
typedef float f32x4 __attribute__((ext_vector_type(4)));

static __device__ __forceinline__ unsigned short f2h(float f) {
    return __builtin_bit_cast(unsigned short, (_Float16)f);  // RNE
}

__global__ void zero_out_kernel(float* __restrict__ out, int n) {
    int i = blockIdx.x * blockDim.x + threadIdx.x;
    if (i < n) out[i] = 0.0f;
}

// Coalesced transpose + fp16 convert via LDS (stride 138 u16: conflict-free).
__global__ __launch_bounds__(256) void prep_weights2(
    const float* __restrict__ Wh, const float* __restrict__ Wo,
    unsigned short* __restrict__ ws) {
    __shared__ unsigned short t_sm[128 * 138];
    unsigned short* wh = ws;
    unsigned short* wo = ws + WH_ELEMS;
    const int b = blockIdx.x;
    const int tid = threadIdx.x;
    if (b < 256) {
        const float* src = Wh + (size_t)b * 16384;  // [k][v]
        for (int i = tid; i < 16384; i += 256) {
            int k = i >> 7, v = i & 127;
            t_sm[v * 138 + k] = f2h(src[i]);  // coalesced read
        }
        __syncthreads();
        unsigned short* dst = wh + (size_t)b * 16384;  // [v][k]
        for (int i = tid; i < 8192; i += 256) {
            int v = i >> 6, kp = i & 63;
            unsigned lo = t_sm[v * 138 + 2 * kp];
            unsigned hi = t_sm[v * 138 + 2 * kp + 1];
            *(unsigned*)&dst[v * 128 + 2 * kp] = lo | (hi << 16);  // coalesced write
        }
    } else {
        const int f = b - 256;
        const float* src = Wo + (size_t)f * 4096;  // [k][o]
        for (int i = tid; i < 4096; i += 256) {
            int k = i >> 5, o = i & 31;
            t_sm[o * 138 + k] = f2h(src[i]);
        }
        __syncthreads();
        unsigned short* dst = wo + (size_t)f * 4096;  // [o][k]
        for (int i = tid; i < 2048; i += 256) {
            int o = i >> 6, kp = i & 63;
            unsigned lo = t_sm[o * 138 + 2 * kp];
            unsigned hi = t_sm[o * 138 + 2 * kp + 1];
            *(unsigned*)&dst[o * 128 + 2 * kp] = lo | (hi << 16);
        }
    }
}

// Fused MLP chain: fp16 operands / fp32 accum. 2x2 wave split; full B[4][4]
// (16 x b128) in registers per layer; next layer's B prefetched pre-barrier.
// launch_bounds(256,3): VGPR cap 170 -> no spill (r7 lesson), 3 blocks/CU.
__global__ __launch_bounds__(256, 3) void ngam_fused(
    const float* __restrict__ x, const float* __restrict__ W1,
    const float* __restrict__ b1, const float* __restrict__ bh,
    const float* __restrict__ bo, const unsigned short* __restrict__ ws,
    float* __restrict__ out) {
    __shared__ __align__(16) unsigned short h_sm[MT * LDH];
    const unsigned short* wh = ws;
    const unsigned short* wo = ws + WH_ELEMS;

    const int fpair = blockIdx.x >> 5;
    const int m0    = (blockIdx.x & 31) * MT;
    const int tid   = threadIdx.x;
    const int wave  = tid >> 6;
    const int lane  = tid & 63;
    const int arow  = lane & 15;
    const int kgrp  = lane >> 4;
    const int wr    = wave >> 1;  // row-half owner (64 rows)
    const int wc    = wave & 1;   // col-half owner (64 cols)
    const int r0    = wave * 32;  // private rows for output stage

    f32x4 oacc[2][2];
    for (int a = 0; a < 2; ++a)
        for (int b = 0; b < 2; ++b) oacc[a][b] = (f32x4){0.f, 0.f, 0.f, 0.f};

    for (int fp = 0; fp < FPB; ++fp) {
        const int f = fpair + fp * (NF / FPB);

        // ---- preload layer-1 B fragments (16 x b128, independent) ----
        f16x8 B[4][4];  // [nt][kt]
        {
            const unsigned short* wp = wh + (size_t)(0 * NF + f) * 16384;
#pragma unroll
            for (int nt = 0; nt < 4; ++nt)
#pragma unroll
                for (int kt = 0; kt < 4; ++kt)
                    B[nt][kt] = *(const f16x8*)&wp[(wc * 64 + nt * 16 + arow) * 128 + kt * 32 + kgrp * 8];
        }

        // ---- layer 0: h = relu(x*W1+b1), fp32 exact -> fp16 LDS ----
        {
            int m = tid >> 1, c = tid & 1;
            float xv = x[(size_t)(m0 + m) * NF + f];
            const float* w1r = &W1[f * NW];
            const float* b1r = &b1[f * NW];
#pragma unroll
            for (int j = 0; j < 16; ++j) {
                int wq = c * 64 + j * 4;
                float4 w1 = *(const float4*)&w1r[wq];
                float4 bb = *(const float4*)&b1r[wq];
                float v0 = fmaxf(xv * w1.x + bb.x, 0.0f);
                float v1 = fmaxf(xv * w1.y + bb.y, 0.0f);
                float v2 = fmaxf(xv * w1.z + bb.z, 0.0f);
                float v3 = fmaxf(xv * w1.w + bb.w, 0.0f);
                *(unsigned*)&h_sm[m * LDH + wq]     = (unsigned)f2h(v0) | ((unsigned)f2h(v1) << 16);
                *(unsigned*)&h_sm[m * LDH + wq + 2] = (unsigned)f2h(v2) | ((unsigned)f2h(v3) << 16);
            }
        }
        __syncthreads();

        // ---- two hidden layers; next stage's B loads issued pre-barrier ----
#pragma unroll
        for (int l = 0; l < 2; ++l) {
            const float* bhl = bh + (size_t)(l * NF + f) * NW;
            f32x4 acc[4][4];  // [mt][nt]
#pragma unroll
            for (int nt = 0; nt < 4; ++nt) {
                float bv = bhl[wc * 64 + nt * 16 + arow];
#pragma unroll
                for (int mt = 0; mt < 4; ++mt) acc[mt][nt] = (f32x4){bv, bv, bv, bv};
            }
#pragma unroll
            for (int mt = 0; mt < 4; ++mt) {
#pragma unroll
                for (int kt = 0; kt < 4; ++kt) {
                    f16x8 a = *(const f16x8*)&h_sm[(wr * 64 + mt * 16 + arow) * LDH + kt * 32 + kgrp * 8];
#pragma unroll
                    for (int nt = 0; nt < 4; ++nt)
                        acc[mt][nt] = __builtin_amdgcn_mfma_f32_16x16x32_f16(a, B[nt][kt], acc[mt][nt], 0, 0, 0);
                }
            }
            // issue next stage's B loads: latency hides under barrier+writeback
            if (l == 0) {
                const unsigned short* wp = wh + (size_t)(1 * NF + f) * 16384;
#pragma unroll
                for (int nt = 0; nt < 4; ++nt)
#pragma unroll
                    for (int kt = 0; kt < 4; ++kt)
                        B[nt][kt] = *(const f16x8*)&wp[(wc * 64 + nt * 16 + arow) * 128 + kt * 32 + kgrp * 8];
            }
            __syncthreads();  // all waves done reading h
#pragma unroll
            for (int mt = 0; mt < 4; ++mt)
#pragma unroll
                for (int nt = 0; nt < 4; ++nt)
#pragma unroll
                    for (int r = 0; r < 4; ++r)
                        h_sm[(wr * 64 + mt * 16 + kgrp * 4 + r) * LDH + wc * 64 + nt * 16 + arow] =
                            f2h(fmaxf(acc[mt][nt][r], 0.0f));
            __syncthreads();  // writeback visible
        }

        // ---- output layer (row-private: wave's 32 rows, 32 cols) ----
        {
            const unsigned short* wp = wo + (size_t)f * 4096;
            const float* bof = bo + (size_t)f * NO;
            f16x8 Bo[2][4];
#pragma unroll
            for (int ntl = 0; ntl < 2; ++ntl)
#pragma unroll
                for (int kt = 0; kt < 4; ++kt)
                    Bo[ntl][kt] = *(const f16x8*)&wp[(ntl * 16 + arow) * 128 + kt * 32 + kgrp * 8];
            f32x4 acc2[2][2];
#pragma unroll
            for (int ntl = 0; ntl < 2; ++ntl) {
                float bv = bof[ntl * 16 + arow];
                acc2[0][ntl] = (f32x4){bv, bv, bv, bv};
                acc2[1][ntl] = acc2[0][ntl];
            }
#pragma unroll
            for (int mt2 = 0; mt2 < 2; ++mt2) {
#pragma unroll
                for (int kt = 0; kt < 4; ++kt) {
                    f16x8 a = *(const f16x8*)&h_sm[(r0 + mt2 * 16 + arow) * LDH + kt * 32 + kgrp * 8];
                    acc2[mt2][0] = __builtin_amdgcn_mfma_f32_16x16x32_f16(a, Bo[0][kt], acc2[mt2][0], 0, 0, 0);
                    acc2[mt2][1] = __builtin_amdgcn_mfma_f32_16x16x32_f16(a, Bo[1][kt], acc2[mt2][1], 0, 0, 0);
                }
            }
#pragma unroll
            for (int mt2 = 0; mt2 < 2; ++mt2)
#pragma unroll
                for (int ntl = 0; ntl < 2; ++ntl) oacc[mt2][ntl] += acc2[mt2][ntl];
        }
        __syncthreads();  // h_sm reads done before next feature's layer-0 fill
    }

    // ---- atomic accumulation over features ----
#pragma unroll
    for (int mt2 = 0; mt2 < 2; ++mt2)
#pragma unroll
        for (int ntl = 0; ntl < 2; ++ntl)
#pragma unroll
            for (int r = 0; r < 4; ++r) {
                int row = m0 + r0 + mt2 * 16 + kgrp * 4 + r;
                int col = ntl * 16 + arow;
                atomicAdd(&out[(size_t)row * NO + col], oacc[mt2][ntl][r]);
            }
}

extern "C" void kernel_launch(void* const* d_in, const int* in_sizes, int n_in,
                              void* d_out, int out_size, void* d_ws, size_t ws_size,
                              hipStream_t stream) {
    const float* x  = (const float*)d_in[0];
    const float* W1 = (const float*)d_in[1];
    const float* b1 = (const float*)d_in[2];
    const float* Wh = (const float*)d_in[3];
    const float* bh = (const float*)d_in[4];
    const float* Wo = (const float*)d_in[5];
    const float* bo = (const float*)d_in[6];
    float* out = (float*)d_out;
    unsigned short* ws = (unsigned short*)d_ws;

    zero_out_kernel<<<(BATCH * NO + 255) / 256, 256, 0, stream>>>(out, BATCH * NO);
    prep_weights2<<<384, 256, 0, stream>>>(Wh, Wo, ws);
    ngam_fused<<<(NF / FPB) * (BATCH / MT), 256, 0, stream>>>(x, W1, b1, bh, bo, ws, out);
}

// Round 9
// 138.874 us; speedup vs baseline: 1.0911x; 1.0911x over previous
//
#include <hip/hip_runtime.h>

#define BATCH 4096
#define NF 128
#define NW 128
#define NO 32
#define MT 128    // batch rows per block
#define LDH 136   // h stride in u16 (272B rows: 16B-aligned)

// d_ws (u16 elems): wh fp16 [l,f][v][k] | wo fp16 [f][o][k]  (k contiguous)
#define WH_ELEMS (2 * 128 * 128 * 128)
#define WO_ELEMS (128 * 128 * 32)

typedef _Float16 f16x8 __attribute__((ext_vector_type(8)));
typedef float f32x4 __attribute__((ext_vector_type(4)));

static __device__ __forceinline__ unsigned short f2h(float f) {
    return __builtin_bit_cast(unsigned short, (_Float16)f);  // RNE
}

__global__ void zero_out_kernel(float* __restrict__ out, int n) {
    int i = blockIdx.x * blockDim.x + threadIdx.x;
    if (i < n) out[i] = 0.0f;
}

// Coalesced transpose + fp16 convert via LDS (stride 138 u16: conflict-free).
__global__ __launch_bounds__(256) void prep_weights2(
    const float* __restrict__ Wh, const float* __restrict__ Wo,
    unsigned short* __restrict__ ws) {
    __shared__ unsigned short t_sm[128 * 138];
    unsigned short* wh = ws;
    unsigned short* wo = ws + WH_ELEMS;
    const int b = blockIdx.x;
    const int tid = threadIdx.x;
    if (b < 256) {
        const float* src = Wh + (size_t)b * 16384;  // [k][v]
        for (int i = tid; i < 16384; i += 256) {
            int k = i >> 7, v = i & 127;
            t_sm[v * 138 + k] = f2h(src[i]);  // coalesced read
        }
        __syncthreads();
        unsigned short* dst = wh + (size_t)b * 16384;  // [v][k]
        for (int i = tid; i < 8192; i += 256) {
            int v = i >> 6, kp = i & 63;
            unsigned lo = t_sm[v * 138 + 2 * kp];
            unsigned hi = t_sm[v * 138 + 2 * kp + 1];
            *(unsigned*)&dst[v * 128 + 2 * kp] = lo | (hi << 16);  // coalesced write
        }
    } else {
        const int f = b - 256;
        const float* src = Wo + (size_t)f * 4096;  // [k][o]
        for (int i = tid; i < 4096; i += 256) {
            int k = i >> 5, o = i & 31;
            t_sm[o * 138 + k] = f2h(src[i]);
        }
        __syncthreads();
        unsigned short* dst = wo + (size_t)f * 4096;  // [o][k]
        for (int i = tid; i < 2048; i += 256) {
            int o = i >> 6, kp = i & 63;
            unsigned lo = t_sm[o * 138 + 2 * kp];
            unsigned hi = t_sm[o * 138 + 2 * kp + 1];
            *(unsigned*)&dst[o * 128 + 2 * kp] = lo | (hi << 16);
        }
    }
}

// Fused MLP chain: fp16 operands / fp32 accum. 2x2 wave split. B held as
// [4][2] k-halves (32 regs) so acc(64)+B(32)+temps fits the 128-reg cap of
// 4 blocks/CU (r7/r8 lesson: acc64+B64 at cap<135 -> accumulator spill).
__global__ __launch_bounds__(256, 4) void ngam_fused(
    const float* __restrict__ x, const float* __restrict__ W1,
    const float* __restrict__ b1, const float* __restrict__ bh,
    const float* __restrict__ bo, const unsigned short* __restrict__ ws,
    float* __restrict__ out) {
    __shared__ __align__(16) unsigned short h_sm[MT * LDH];
    const unsigned short* wh = ws;
    const unsigned short* wo = ws + WH_ELEMS;

    const int f    = blockIdx.x >> 5;        // feature (32 batch tiles each)
    const int m0   = (blockIdx.x & 31) * MT;
    const int tid  = threadIdx.x;
    const int wave = tid >> 6;
    const int lane = tid & 63;
    const int arow = lane & 15;
    const int kgrp = lane >> 4;
    const int wr   = wave >> 1;  // row-half owner (64 rows)
    const int wc   = wave & 1;   // col-half owner (64 cols)
    const int r0   = wave * 32;  // private rows for output stage

    // ---- layer 0: h = relu(x*W1+b1), fp32 exact -> fp16 LDS ----
    {
        int m = tid >> 1, c = tid & 1;
        float xv = x[(size_t)(m0 + m) * NF + f];
        const float* w1r = &W1[f * NW];
        const float* b1r = &b1[f * NW];
#pragma unroll
        for (int j = 0; j < 16; ++j) {
            int wq = c * 64 + j * 4;
            float4 w1 = *(const float4*)&w1r[wq];
            float4 bb = *(const float4*)&b1r[wq];
            float v0 = fmaxf(xv * w1.x + bb.x, 0.0f);
            float v1 = fmaxf(xv * w1.y + bb.y, 0.0f);
            float v2 = fmaxf(xv * w1.z + bb.z, 0.0f);
            float v3 = fmaxf(xv * w1.w + bb.w, 0.0f);
            *(unsigned*)&h_sm[m * LDH + wq]     = (unsigned)f2h(v0) | ((unsigned)f2h(v1) << 16);
            *(unsigned*)&h_sm[m * LDH + wq + 2] = (unsigned)f2h(v2) | ((unsigned)f2h(v3) << 16);
        }
    }
    __syncthreads();

    // ---- two hidden layers ----
#pragma unroll
    for (int l = 0; l < 2; ++l) {
        const unsigned short* wp = wh + (size_t)(l * NF + f) * 16384;
        const float* bhl = bh + (size_t)(l * NF + f) * NW;
        f32x4 acc[4][4];  // [mt][nt]
#pragma unroll
        for (int nt = 0; nt < 4; ++nt) {
            float bv = bhl[wc * 64 + nt * 16 + arow];
#pragma unroll
            for (int mt = 0; mt < 4; ++mt) acc[mt][nt] = (f32x4){bv, bv, bv, bv};
        }
#pragma unroll
        for (int kh = 0; kh < 2; ++kh) {   // k-half: B residency 32 regs
            f16x8 B[4][2];                 // [nt][kt2], kt = kh*2+kt2
#pragma unroll
            for (int nt = 0; nt < 4; ++nt)
#pragma unroll
                for (int kt2 = 0; kt2 < 2; ++kt2)
                    B[nt][kt2] = *(const f16x8*)&wp[(wc * 64 + nt * 16 + arow) * 128 +
                                                    (kh * 2 + kt2) * 32 + kgrp * 8];
#pragma unroll
            for (int mt = 0; mt < 4; ++mt) {
#pragma unroll
                for (int kt2 = 0; kt2 < 2; ++kt2) {
                    f16x8 a = *(const f16x8*)&h_sm[(wr * 64 + mt * 16 + arow) * LDH +
                                                   (kh * 2 + kt2) * 32 + kgrp * 8];
#pragma unroll
                    for (int nt = 0; nt < 4; ++nt)
                        acc[mt][nt] = __builtin_amdgcn_mfma_f32_16x16x32_f16(a, B[nt][kt2], acc[mt][nt], 0, 0, 0);
                }
            }
        }
        __syncthreads();  // all waves done reading h
#pragma unroll
        for (int mt = 0; mt < 4; ++mt)
#pragma unroll
            for (int nt = 0; nt < 4; ++nt)
#pragma unroll
                for (int r = 0; r < 4; ++r)
                    h_sm[(wr * 64 + mt * 16 + kgrp * 4 + r) * LDH + wc * 64 + nt * 16 + arow] =
                        f2h(fmaxf(acc[mt][nt][r], 0.0f));
        __syncthreads();  // writeback visible
    }

    // ---- output layer (row-private: wave's 32 rows, 32 cols) + atomics ----
    {
        const unsigned short* wop = wo + (size_t)f * 4096;
        const float* bof = bo + (size_t)f * NO;
        f16x8 Bo[2][4];
#pragma unroll
        for (int ntl = 0; ntl < 2; ++ntl)
#pragma unroll
            for (int kt = 0; kt < 4; ++kt)
                Bo[ntl][kt] = *(const f16x8*)&wop[(ntl * 16 + arow) * 128 + kt * 32 + kgrp * 8];
        f32x4 acc2[2][2];
#pragma unroll
        for (int ntl = 0; ntl < 2; ++ntl) {
            float bv = bof[ntl * 16 + arow];
            acc2[0][ntl] = (f32x4){bv, bv, bv, bv};
            acc2[1][ntl] = acc2[0][ntl];
        }
#pragma unroll
        for (int mt2 = 0; mt2 < 2; ++mt2) {
#pragma unroll
            for (int kt = 0; kt < 4; ++kt) {
                f16x8 a = *(const f16x8*)&h_sm[(r0 + mt2 * 16 + arow) * LDH + kt * 32 + kgrp * 8];
                acc2[mt2][0] = __builtin_amdgcn_mfma_f32_16x16x32_f16(a, Bo[0][kt], acc2[mt2][0], 0, 0, 0);
                acc2[mt2][1] = __builtin_amdgcn_mfma_f32_16x16x32_f16(a, Bo[1][kt], acc2[mt2][1], 0, 0, 0);
            }
        }
#pragma unroll
        for (int mt2 = 0; mt2 < 2; ++mt2)
#pragma unroll
            for (int ntl = 0; ntl < 2; ++ntl)
#pragma unroll
                for (int r = 0; r < 4; ++r) {
                    int row = m0 + r0 + mt2 * 16 + kgrp * 4 + r;
                    int col = ntl * 16 + arow;
                    atomicAdd(&out[(size_t)row * NO + col], acc2[mt2][ntl][r]);
                }
    }
}

extern "C" void kernel_launch(void* const* d_in, const int* in_sizes, int n_in,
                              void* d_out, int out_size, void* d_ws, size_t ws_size,
                              hipStream_t stream) {
    const float* x  = (const float*)d_in[0];
    const float* W1 = (const float*)d_in[1];
    const float* b1 = (const float*)d_in[2];
    const float* Wh = (const float*)d_in[3];
    const float* bh = (const float*)d_in[4];
    const float* Wo = (const float*)d_in[5];
    const float* bo = (const float*)d_in[6];
    float* out = (float*)d_out;
    unsigned short* ws = (unsigned short*)d_ws;

    zero_out_kernel<<<(BATCH * NO + 255) / 256, 256, 0, stream>>>(out, BATCH * NO);
    prep_weights2<<<384, 256, 0, stream>>>(Wh, Wo, ws);
    ngam_fused<<<NF * (BATCH / MT), 256, 0, stream>>>(x, W1, b1, bh, bo, ws, out);
}